// Round 8
// baseline (70.936 us; speedup 1.0000x reference)
//
#include <hip/hip_runtime.h>
#include <stdint.h>

#define N 4096
#define D 512
#define L 512
#define NHALF 8388608u   // 2^23 = N*N/2
#define MARGIN_F 2.0f
#define EPS_F 1e-11f
#define PAIR_CAP 20480   // expected ~16.4K pairs; 8.6 sigma headroom
#define DOT_BLOCKS 1024

// Exact JAX threefry2x32 with key (0,1)  [jax.random.key(1) -> data (0,1)]
__device__ __forceinline__ void threefry2x32_01(uint32_t& x0, uint32_t& x1) {
    const uint32_t ks0 = 0u, ks1 = 1u, ks2 = 0x1BD11BDBu;
    x0 += ks0; x1 += ks1;
#define TF_R(R) { x0 += x1; x1 = (x1 << (R)) | (x1 >> (32 - (R))); x1 ^= x0; }
    TF_R(13) TF_R(15) TF_R(26) TF_R(6)
    x0 += ks1; x1 += ks2 + 1u;
    TF_R(17) TF_R(29) TF_R(16) TF_R(24)
    x0 += ks2; x1 += ks0 + 2u;
    TF_R(13) TF_R(15) TF_R(26) TF_R(6)
    x0 += ks0; x1 += ks1 + 3u;
    TF_R(17) TF_R(29) TF_R(16) TF_R(24)
    x0 += ks1; x1 += ks2 + 4u;
    TF_R(13) TF_R(15) TF_R(26) TF_R(6)
    x0 += ks2; x1 += ks0 + 5u;
#undef TF_R
}

__device__ __forceinline__ void argmax_combine(uint32_t& v, int& j, uint32_t ov, int oj) {
    if (ov > v || (ov == v && oj < j)) { v = ov; j = oj; }
}

// K1: threefry gumbel-argmax neg_idx (exact jax.random.categorical reproduction).
// Block i0 in [0,2048): rows i0 (hash out0) and i0+2048 (hash out1).
__global__ void k_prep(const int* __restrict__ labels, int* __restrict__ neg_idx) {
    int i0 = blockIdx.x;
    int t = threadIdx.x, w = t >> 6, lane = t & 63;
    int lab0 = labels[i0], lab1 = labels[i0 + 2048];
    uint32_t v0 = 0u, v1 = 0u;
    int j0 = 0x7fffffff, j1 = 0x7fffffff;
    bool h0 = false, h1 = false;
    for (int j = t; j < N; j += 256) {
        uint32_t p = (uint32_t)(i0 * N + j);
        uint32_t x0 = p, x1 = p + NHALF;
        threefry2x32_01(x0, x1);
        uint32_t b0 = x0 >> 9, b1 = x1 >> 9;   // 23-bit draw, monotone in gumbel
        int lj = labels[j];
        if (lj != lab0) { if (!h0 || b0 > v0) { v0 = b0; j0 = j; h0 = true; } }
        if (lj != lab1) { if (!h1 || b1 > v1) { v1 = b1; j1 = j; h1 = true; } }
    }
    for (int m = 32; m; m >>= 1) {
        uint32_t ov = __shfl_xor(v0, m, 64); int oj = __shfl_xor(j0, m, 64);
        argmax_combine(v0, j0, ov, oj);
        ov = __shfl_xor(v1, m, 64); oj = __shfl_xor(j1, m, 64);
        argmax_combine(v1, j1, ov, oj);
    }
    __shared__ uint32_t sv0[4], sv1[4];
    __shared__ int sj0[4], sj1[4];
    if (lane == 0) { sv0[w] = v0; sj0[w] = j0; sv1[w] = v1; sj1[w] = j1; }
    __syncthreads();
    if (t == 0) {
        uint32_t bv = sv0[0]; int bj = sj0[0];
        for (int k = 1; k < 4; k++) argmax_combine(bv, bj, sv0[k], sj0[k]);
        neg_idx[i0] = (bj == 0x7fffffff) ? -1 : bj;
        bv = sv1[0]; bj = sj1[0];
        for (int k = 1; k < 4; k++) argmax_combine(bv, bj, sv1[k], sj1[k]);
        neg_idx[i0 + 2048] = (bj == 0x7fffffff) ? -1 : bj;
    }
}

// K2: single block, 512 threads (thread t = label t). Labels scanned ONCE into
// LDS CSR; per-label sort (deterministic order); emit flat valid-pair list
// (anchor i = min index, requires has_neg[i]) + exact pair count.
__global__ void __launch_bounds__(512) k_pairlist(const int* __restrict__ labels,
                                                  const int* __restrict__ neg_idx,
                                                  uint32_t* __restrict__ pairs,
                                                  int* __restrict__ meta) {
    __shared__ unsigned short csr[N];
    __shared__ int hist[L];
    __shared__ int cur[L];
    __shared__ int sA[L], sB[L];
    __shared__ unsigned char has[N];
    int t = threadIdx.x;
    hist[t] = 0;
    __syncthreads();
    int lab[8];
    for (int k = 0; k < 8; k++) {
        int j = t + k * L;
        lab[k] = labels[j];
        atomicAdd(&hist[lab[k]], 1);
        has[j] = (neg_idx[j] >= 0) ? 1 : 0;
    }
    __syncthreads();
    // inclusive scan of hist (ping-pong)
    sA[t] = hist[t];
    __syncthreads();
    int* src = sA; int* dst = sB;
    for (int off = 1; off < L; off <<= 1) {
        dst[t] = src[t] + ((t >= off) ? src[t - off] : 0);
        __syncthreads();
        int* tmp = src; src = dst; dst = tmp;
    }
    int c = hist[t];
    int beg = src[t] - c;          // saved to registers before arrays are reused
    cur[t] = beg;
    __syncthreads();
    for (int k = 0; k < 8; k++) {
        int j = t + k * L;
        int p = atomicAdd(&cur[lab[k]], 1);
        csr[p] = (unsigned short)j;
    }
    __syncthreads();
    // sort own bucket ascending -> deterministic emission, and a<b => row_a<row_b
    for (int a = 1; a < c; a++) {
        unsigned short key = csr[beg + a]; int b = a - 1;
        while (b >= 0 && csr[beg + b] > key) { csr[beg + b + 1] = csr[beg + b]; b--; }
        csr[beg + b + 1] = key;
    }
    // count valid pairs for this label
    int nv = 0;
    for (int a = 0; a + 1 < c; a++) {
        int ia = csr[beg + a];
        if (has[ia]) nv += (c - 1 - a);
    }
    __syncthreads();
    // scan nv -> per-label output base
    sA[t] = nv;
    __syncthreads();
    src = sA; dst = sB;
    for (int off = 1; off < L; off <<= 1) {
        dst[t] = src[t] + ((t >= off) ? src[t - off] : 0);
        __syncthreads();
        int* tmp = src; src = dst; dst = tmp;
    }
    int slot = src[t] - nv;
    int total = src[L - 1];
    for (int a = 0; a + 1 < c; a++) {
        int ia = csr[beg + a];
        if (!has[ia]) continue;
        for (int b = a + 1; b < c; b++) {
            int jb = csr[beg + b];
            if (slot < PAIR_CAP) pairs[slot] = (uint32_t)ia | ((uint32_t)jb << 16);
            slot++;
        }
    }
    if (t == 0) meta[0] = (total > PAIR_CAP) ? PAIR_CAP : total;
}

// K3: one wave per pair (grid-stride). dist(i,j) and dist(i,neg_i) via direct
// sum-of-squared-diffs, two interleaved shfl reductions. No atomics, no fences:
// per-block partial to its own slot (written unconditionally by every block).
__global__ void k_dots(const float* __restrict__ F, const int* __restrict__ neg_idx,
                       const uint32_t* __restrict__ pairs, const int* __restrict__ meta,
                       float* __restrict__ partials) {
    int t = threadIdx.x, w = t >> 6, lane = t & 63;
    int np = meta[0];
    int gw = blockIdx.x * 4 + w;
    const int nw = DOT_BLOCKS * 4;
    float tot = 0.f;
    for (int p = gw; p < np; p += nw) {
        uint32_t pr = pairs[p];
        int i = (int)(pr & 0xffffu);
        int j = (int)(pr >> 16);
        int n = neg_idx[i];
        const float4* fi = (const float4*)(F + (size_t)i * D);
        const float4* fj = (const float4*)(F + (size_t)j * D);
        const float4* fn = (const float4*)(F + (size_t)n * D);
        float4 a0 = fi[lane*2], a1 = fi[lane*2+1];
        float4 b0 = fj[lane*2], b1 = fj[lane*2+1];
        float4 c0 = fn[lane*2], c1 = fn[lane*2+1];
        float d, s1 = 0.f, s2 = 0.f;
        d = a0.x-b0.x; s1 += d*d;  d = a0.x-c0.x; s2 += d*d;
        d = a0.y-b0.y; s1 += d*d;  d = a0.y-c0.y; s2 += d*d;
        d = a0.z-b0.z; s1 += d*d;  d = a0.z-c0.z; s2 += d*d;
        d = a0.w-b0.w; s1 += d*d;  d = a0.w-c0.w; s2 += d*d;
        d = a1.x-b1.x; s1 += d*d;  d = a1.x-c1.x; s2 += d*d;
        d = a1.y-b1.y; s1 += d*d;  d = a1.y-c1.y; s2 += d*d;
        d = a1.z-b1.z; s1 += d*d;  d = a1.z-c1.z; s2 += d*d;
        d = a1.w-b1.w; s1 += d*d;  d = a1.w-c1.w; s2 += d*d;
        for (int m = 32; m; m >>= 1) {
            s1 += __shfl_xor(s1, m, 64);
            s2 += __shfl_xor(s2, m, 64);
        }
        float dist = sqrtf(fmaxf(s1, EPS_F));
        float nd   = sqrtf(fmaxf(s2, EPS_F));
        tot += fmaxf(MARGIN_F + dist - nd, 0.f);
    }
    __shared__ float wt[4];
    if (lane == 0) wt[w] = tot;
    __syncthreads();
    if (t == 0) partials[blockIdx.x] = wt[0] + wt[1] + wt[2] + wt[3];
}

// K4: reduce partials, divide by exact pair count.
__global__ void k_final(const float* __restrict__ partials, const int* __restrict__ meta,
                        float* __restrict__ out) {
    int t = threadIdx.x, w = t >> 6, lane = t & 63;  // 256 threads
    float s = 0.f;
    for (int k = t; k < DOT_BLOCKS; k += 256) s += partials[k];
    for (int m = 32; m; m >>= 1) s += __shfl_xor(s, m, 64);
    __shared__ float wt[4];
    if (lane == 0) wt[w] = s;
    __syncthreads();
    if (t == 0) {
        float tot = wt[0] + wt[1] + wt[2] + wt[3];
        int c = meta[0];
        out[0] = (c > 0) ? (tot / (float)c) : 0.f;
    }
}

extern "C" void kernel_launch(void* const* d_in, const int* in_sizes, int n_in,
                              void* d_out, int out_size, void* d_ws, size_t ws_size,
                              hipStream_t stream) {
    const float* F      = (const float*)d_in[0];
    const int*   labels = (const int*)d_in[1];
    float* out = (float*)d_out;

    // workspace layout
    uint32_t* pairs    = (uint32_t*)d_ws;                          // 20480 u32 = 80 KB @ 0
    int*      neg_idx  = (int*)((char*)d_ws + 81920);              // 4096 i  @ 80 KB
    float*    partials = (float*)((char*)d_ws + 98304);            // 1024 f  @ 96 KB
    int*      meta     = (int*)((char*)d_ws + 102400);             // few i   @ 100 KB

    k_prep    <<<N / 2,     256, 0, stream>>>(labels, neg_idx);
    k_pairlist<<<1,         512, 0, stream>>>(labels, neg_idx, pairs, meta);
    k_dots    <<<DOT_BLOCKS,256, 0, stream>>>(F, neg_idx, pairs, meta, partials);
    k_final   <<<1,         256, 0, stream>>>(partials, meta, out);
}

// Round 9
// 38.210 us; speedup vs baseline: 1.8565x; 1.8565x over previous
//
#include <hip/hip_runtime.h>
#include <stdint.h>

#define N 4096
#define D 512
#define NHALF 8388608u   // 2^23 = N*N/2
#define MARGIN_F 2.0f
#define EPS_F 1e-11f
#define MAXP 96          // max positives per anchor (bucket max ~25; huge margin)

// Exact JAX threefry2x32 with key (0,1)  [jax.random.key(1) -> data (0,1)]
__device__ __forceinline__ void threefry2x32_01(uint32_t& x0, uint32_t& x1) {
    const uint32_t ks0 = 0u, ks1 = 1u, ks2 = 0x1BD11BDBu;
    x0 += ks0; x1 += ks1;
#define TF_R(R) { x0 += x1; x1 = (x1 << (R)) | (x1 >> (32 - (R))); x1 ^= x0; }
    TF_R(13) TF_R(15) TF_R(26) TF_R(6)
    x0 += ks1; x1 += ks2 + 1u;
    TF_R(17) TF_R(29) TF_R(16) TF_R(24)
    x0 += ks2; x1 += ks0 + 2u;
    TF_R(13) TF_R(15) TF_R(26) TF_R(6)
    x0 += ks0; x1 += ks1 + 3u;
    TF_R(17) TF_R(29) TF_R(16) TF_R(24)
    x0 += ks1; x1 += ks2 + 4u;
    TF_R(13) TF_R(15) TF_R(26) TF_R(6)
    x0 += ks2; x1 += ks0 + 5u;
#undef TF_R
}

__device__ __forceinline__ void argmax_combine(uint32_t& v, int& j, uint32_t ov, int oj) {
    // larger draw wins; exact tie -> smaller index (matches jnp.argmax first-index)
    if (ov > v || (ov == v && oj < j)) { v = ov; j = oj; }
}

// wave-wide squared Euclidean distance between rows A and B (512 floats)
__device__ __forceinline__ float wave_sqdiff(const float* __restrict__ A,
                                             const float* __restrict__ B, int lane) {
    const float4* a = (const float4*)A;
    const float4* b = (const float4*)B;
    float4 x0 = a[lane*2], x1 = a[lane*2+1];
    float4 y0 = b[lane*2], y1 = b[lane*2+1];
    float d, s = 0.f;
    d = x0.x-y0.x; s += d*d;  d = x0.y-y0.y; s += d*d;
    d = x0.z-y0.z; s += d*d;  d = x0.w-y0.w; s += d*d;
    d = x1.x-y1.x; s += d*d;  d = x1.y-y1.y; s += d*d;
    d = x1.z-y1.z; s += d*d;  d = x1.w-y1.w; s += d*d;
    for (int m = 32; m; m >>= 1) s += __shfl_xor(s, m, 64);
    return s;
}

// Fused kernel: block i0 owns rows r0=i0 and r1=i0+2048 (threefry pair outputs).
// One scan over j: threefry gumbel-argmax (negative sampling, exact
// jax.random.categorical) + positive collection (same label, j > row).
// Then wave-parallel sq-dist tasks, hinge, block-local reduce. No atomics to HBM.
__global__ void __launch_bounds__(256) k_main(const float* __restrict__ F,
                                              const int* __restrict__ labels,
                                              float* __restrict__ partials,
                                              int* __restrict__ counts) {
    int i0 = blockIdx.x;
    int t = threadIdx.x, w = t >> 6, lane = t & 63;
    int r0 = i0, r1 = i0 + 2048;
    int lab0 = labels[r0], lab1 = labels[r1];

    __shared__ int pos0[MAXP], pos1[MAXP];
    __shared__ int nsh[2];
    __shared__ uint32_t sv0[4], sv1[4];
    __shared__ int sj0[4], sj1[4];
    __shared__ int snk[2];
    __shared__ float sd[2 + 2 * MAXP];   // [0]=negsq0, [1]=negsq1, [2+k], [2+MAXP+k]
    __shared__ float wtot[4];
    __shared__ int wcnt[4];

    if (t < 2) nsh[t] = 0;
    __syncthreads();

    // ---- phase 1: single scan — threefry argmax + positive collection ----
    uint32_t v0 = 0u, v1 = 0u;
    int j0 = 0x7fffffff, j1 = 0x7fffffff;
    bool h0 = false, h1 = false;
    for (int j = t; j < N; j += 256) {
        uint32_t p = (uint32_t)(i0 * N + j);
        uint32_t x0 = p, x1 = p + NHALF;
        threefry2x32_01(x0, x1);
        uint32_t b0 = x0 >> 9, b1 = x1 >> 9;   // 23-bit draw, monotone in gumbel
        int lj = labels[j];
        if (lj != lab0) { if (!h0 || b0 > v0) { v0 = b0; j0 = j; h0 = true; } }
        else if (j > r0) { int q = atomicAdd(&nsh[0], 1); if (q < MAXP) pos0[q] = j; }
        if (lj != lab1) { if (!h1 || b1 > v1) { v1 = b1; j1 = j; h1 = true; } }
        else if (j > r1) { int q = atomicAdd(&nsh[1], 1); if (q < MAXP) pos1[q] = j; }
    }
    for (int m = 32; m; m >>= 1) {
        uint32_t ov = __shfl_xor(v0, m, 64); int oj = __shfl_xor(j0, m, 64);
        argmax_combine(v0, j0, ov, oj);
        ov = __shfl_xor(v1, m, 64); oj = __shfl_xor(j1, m, 64);
        argmax_combine(v1, j1, ov, oj);
    }
    if (lane == 0) { sv0[w] = v0; sj0[w] = j0; sv1[w] = v1; sj1[w] = j1; }
    __syncthreads();
    if (t == 0) {
        uint32_t bv = sv0[0]; int bj = sj0[0];
        for (int k = 1; k < 4; k++) argmax_combine(bv, bj, sv0[k], sj0[k]);
        snk[0] = (bj == 0x7fffffff) ? -1 : bj;
        bv = sv1[0]; bj = sj1[0];
        for (int k = 1; k < 4; k++) argmax_combine(bv, bj, sv1[k], sj1[k]);
        snk[1] = (bj == 0x7fffffff) ? -1 : bj;
    }
    __syncthreads();

    // ---- phase 2: wave-parallel sq-dist tasks (2 neg + n0 + n1 pos) ----
    int n0 = min(nsh[0], MAXP), n1 = min(nsh[1], MAXP);
    int neg0 = snk[0], neg1 = snk[1];
    int ntask = 2 + n0 + n1;
    for (int tk = w; tk < ntask; tk += 4) {
        int a, b, slot;
        if (tk == 0)          { a = r0; b = (neg0 >= 0) ? neg0 : r0; slot = 0; }
        else if (tk == 1)     { a = r1; b = (neg1 >= 0) ? neg1 : r1; slot = 1; }
        else if (tk < 2 + n0) { a = r0; b = pos0[tk - 2];            slot = tk; }
        else                  { a = r1; b = pos1[tk - 2 - n0];       slot = 2 + MAXP + (tk - 2 - n0); }
        float s = wave_sqdiff(F + (size_t)a * D, F + (size_t)b * D, lane);
        if (lane == 0) sd[slot] = s;
    }
    __syncthreads();

    // ---- phase 3: hinge terms + block reduce ----
    float nd0 = sqrtf(fmaxf(sd[0], EPS_F));
    float nd1 = sqrtf(fmaxf(sd[1], EPS_F));
    float tot = 0.f; int cnt = 0;
    for (int k = t; k < n0 + n1; k += 256) {
        float dsq, nd; bool ok;
        if (k < n0) { dsq = sd[2 + k];               nd = nd0; ok = (neg0 >= 0); }
        else        { dsq = sd[2 + MAXP + (k - n0)]; nd = nd1; ok = (neg1 >= 0); }
        if (ok) { tot += fmaxf(MARGIN_F + sqrtf(fmaxf(dsq, EPS_F)) - nd, 0.f); cnt++; }
    }
    for (int m = 32; m; m >>= 1) {
        tot += __shfl_xor(tot, m, 64);
        cnt += __shfl_xor(cnt, m, 64);
    }
    if (lane == 0) { wtot[w] = tot; wcnt[w] = cnt; }
    __syncthreads();
    if (t == 0) {
        partials[i0] = wtot[0] + wtot[1] + wtot[2] + wtot[3];
        counts[i0]   = wcnt[0] + wcnt[1] + wcnt[2] + wcnt[3];
    }
}

// Reduce 2048 partials + counts -> mean
__global__ void k_reduce(const float* __restrict__ partials, const int* __restrict__ counts,
                         float* __restrict__ out) {
    int t = threadIdx.x, w = t >> 6, lane = t & 63;
    float s = 0.f; int c = 0;
    for (int k = t; k < 2048; k += 256) { s += partials[k]; c += counts[k]; }
    for (int m = 32; m; m >>= 1) {
        s += __shfl_xor(s, m, 64);
        c += __shfl_xor(c, m, 64);
    }
    __shared__ float ws[4]; __shared__ int wc[4];
    if (lane == 0) { ws[w] = s; wc[w] = c; }
    __syncthreads();
    if (t == 0) {
        float T = ws[0] + ws[1] + ws[2] + ws[3];
        int   C = wc[0] + wc[1] + wc[2] + wc[3];
        out[0] = (C > 0) ? (T / (float)C) : 0.f;
    }
}

extern "C" void kernel_launch(void* const* d_in, const int* in_sizes, int n_in,
                              void* d_out, int out_size, void* d_ws, size_t ws_size,
                              hipStream_t stream) {
    const float* F      = (const float*)d_in[0];
    const int*   labels = (const int*)d_in[1];
    float* out = (float*)d_out;

    float* partials = (float*)d_ws;                    // 2048 f @ 0
    int*   counts   = (int*)((char*)d_ws + 8192);      // 2048 i @ 8K

    k_main  <<<N / 2, 256, 0, stream>>>(F, labels, partials, counts);
    k_reduce<<<1,     256, 0, stream>>>(partials, counts, out);
}